// Round 13
// baseline (559.573 us; speedup 1.0000x reference)
//
#include <hip/hip_runtime.h>
#include <hip/hip_bf16.h>
#include <math.h>

#define NN 20000
#define EE 320000
#define DD 256
#define TT 8
#define RR 8
#define HH 8
#define LLAYERS 2
#define RELN (LLAYERS * RR * HH * 1024)
#define NBN 79   // node blocks (79*256 >= 20000)

typedef __attribute__((ext_vector_type(8))) short short8;
typedef __attribute__((ext_vector_type(4))) float f32x4;
typedef __attribute__((ext_vector_type(4))) unsigned short us4;
typedef __attribute__((ext_vector_type(8))) unsigned short us8;

__device__ __forceinline__ float b2f(unsigned short u) {
    return __uint_as_float(((unsigned int)u) << 16);
}
__device__ __forceinline__ unsigned short f2b(float f) {
    unsigned int x = __float_as_uint(f);
    unsigned int r = (x + 0x7fffu + ((x >> 16) & 1u)) >> 16;
    return (unsigned short)r;
}

// ---------- one-shot prep: nf conv + relA conv + relM transposed conv ----------
__global__ void k_prep(const float* __restrict__ nf, const float* __restrict__ rA,
                       const float* __restrict__ rM,
                       unsigned short* __restrict__ nf_bf, unsigned short* __restrict__ relA,
                       unsigned short* __restrict__ relMT) {
    int idx = blockIdx.x * 256 + threadIdx.x;
    const int n0 = NN * 256;
    if (idx < n0) { nf_bf[idx] = f2b(nf[idx]); return; }
    idx -= n0;
    if (idx < RELN) { relA[idx] = f2b(rA[idx]); return; }
    idx -= RELN;
    if (idx < RELN) {
        int g = idx >> 10, loc = idx & 1023;
        int a = loc >> 5, b = loc & 31;
        // relMT[g][e][d] = rM[g][d][e]  (32x32 block transpose)
        relMT[(size_t)g * 1024 + a * 32 + b] = f2b(rM[(size_t)g * 1024 + b * 32 + a]);
    }
}

// ---------- all weight transposes in one kernel ----------
__global__ void k_transpose_all(const float* __restrict__ adW, const float* __restrict__ kW,
                                const float* __restrict__ qW, const float* __restrict__ vW,
                                const float* __restrict__ aW, unsigned short* __restrict__ out) {
    __shared__ float tile[32][33];
    int z = blockIdx.z;
    const float* ip;
    if (z < 8) ip = adW + (size_t)z * 65536;
    else if (z < 24) ip = kW + (size_t)(z - 8) * 65536;
    else if (z < 40) ip = qW + (size_t)(z - 24) * 65536;
    else if (z < 56) ip = vW + (size_t)(z - 40) * 65536;
    else ip = aW + (size_t)(z - 56) * 65536;
    unsigned short* op = out + (size_t)z * 65536;
    int ox = blockIdx.x * 32, dy = blockIdx.y * 32;
    int tx = threadIdx.x, ty = threadIdx.y; // 32 x 8
#pragma unroll
    for (int r = 0; r < 4; r++) tile[ty + 8 * r][tx] = ip[(size_t)(dy + ty + 8 * r) * 256 + ox + tx];
    __syncthreads();
#pragma unroll
    for (int r = 0; r < 4; r++) op[(size_t)(ox + ty + 8 * r) * 256 + dy + tx] = f2b(tile[tx][ty + 8 * r]);
}

// ---------- graph build ----------
__global__ void k_build1(const int* __restrict__ ei, const int* __restrict__ nt,
                         int* __restrict__ deg8, int* __restrict__ thist,
                         int* __restrict__ rank) {
    __shared__ int ltc[TT];
    int i = blockIdx.x * 256 + threadIdx.x;
    int vx = blockIdx.x & 7;
    if (i < EE) {
        int d = ei[EE + i];
        int lr = atomicAdd(&deg8[vx * NN + d], 1);
        rank[i] = (vx << 16) | lr;
    }
    if (blockIdx.x < NBN) {
        if (threadIdx.x < TT) ltc[threadIdx.x] = 0;
        __syncthreads();
        int n = blockIdx.x * 256 + threadIdx.x;
        if (n < NN) atomicAdd(&ltc[nt[n]], 1);
        __syncthreads();
        if (threadIdx.x < TT) thist[blockIdx.x * TT + threadIdx.x] = ltc[threadIdx.x];
    }
}

__global__ __launch_bounds__(256) void k_scanA(const int* __restrict__ deg8,
                                               int* __restrict__ degT,
                                               int* __restrict__ bsum) {
    __shared__ int red[256];
    int b = blockIdx.x, t = threadIdx.x;
    int n = b * 256 + t;
    int tot = 0;
    if (n < NN) {
#pragma unroll
        for (int vx = 0; vx < 8; vx++) tot += deg8[vx * NN + n];
        degT[n] = tot;
    }
    red[t] = tot;
    __syncthreads();
    for (int d = 128; d >= 1; d >>= 1) {
        if (t < d) red[t] += red[t + d];
        __syncthreads();
    }
    if (t == 0) bsum[b] = red[0];
}

__global__ void k_scanB(const int* __restrict__ bsum, int* __restrict__ bbase,
                        int* __restrict__ off,
                        const int* __restrict__ thist, int* __restrict__ toff,
                        int* __restrict__ tboff) {
    __shared__ int partial[TT];
    __shared__ int toff_l[TT + 1];
    int tid = threadIdx.x;
    if (tid == 0) {
        int a = 0;
        for (int b = 0; b < NBN; b++) { bbase[b] = a; a += bsum[b]; }
        off[NN] = EE;
    }
    if (tid < TT) {
        int tot = 0;
        for (int b = 0; b < NBN; b++) tot += thist[b * TT + tid];
        partial[tid] = tot;
    }
    __syncthreads();
    if (tid == 0) {
        int a = 0;
        for (int t = 0; t < TT; t++) { toff_l[t] = a; toff[t] = a; a += partial[t]; }
        toff_l[TT] = a; toff[TT] = a;
    }
    __syncthreads();
    if (tid < TT) {
        int r = toff_l[tid];
        for (int b = 0; b < NBN; b++) { tboff[b * TT + tid] = r; r += thist[b * TT + tid]; }
    }
}

__global__ __launch_bounds__(256) void k_scanC(const int* __restrict__ deg8,
                                               const int* __restrict__ degT,
                                               const int* __restrict__ bbase,
                                               int* __restrict__ off,
                                               int* __restrict__ base8) {
    __shared__ int s[256];
    int b = blockIdx.x, t = threadIdx.x;
    int n = b * 256 + t;
    int v = (n < NN) ? degT[n] : 0;
    s[t] = v;
    __syncthreads();
    for (int d = 1; d < 256; d <<= 1) {
        int x = (t >= d) ? s[t - d] : 0;
        __syncthreads();
        s[t] += x;
        __syncthreads();
    }
    if (n < NN) {
        int run = bbase[b] + s[t] - v;   // exclusive prefix
        off[n] = run;
#pragma unroll
        for (int vx = 0; vx < 8; vx++) {
            base8[vx * NN + n] = run;
            run += deg8[vx * NN + n];
        }
    }
}

// atomic-free CSR fill (one packed 16B scatter/edge) + atomic-free nlist
__global__ void k_build2(const int* __restrict__ ei, const int* __restrict__ et,
                         const float* __restrict__ ew, const int* __restrict__ nt,
                         const int* __restrict__ base8, const int* __restrict__ tboff,
                         const int* __restrict__ rank,
                         int4* __restrict__ csr, int* __restrict__ nlist) {
    __shared__ int ltc[TT];
    int i = blockIdx.x * 256 + threadIdx.x;
    if (i < EE) {
        int d = ei[EE + i];
        int rk = rank[i];
        int p = base8[(rk >> 16) * NN + d] + (rk & 0xffff);
        int4 pk;
        pk.x = ei[i] | (et[i] << 16);
        pk.y = __float_as_int(ew[i]);
        pk.z = d;
        pk.w = i;
        csr[p] = pk;
    }
    if (blockIdx.x < NBN) {
        if (threadIdx.x < TT) ltc[threadIdx.x] = 0;
        __syncthreads();
        int n = blockIdx.x * 256 + threadIdx.x;
        if (n < NN) {
            int t = nt[n];
            int pos = atomicAdd(&ltc[t], 1);
            nlist[tboff[blockIdx.x * TT + t] + pos] = n;
        }
    }
}

// ---------- type-grouped GEMM (64 rows x 256 cols, K=256) ----------
#define LDA 264

__device__ __forceinline__ void gemm_core(const unsigned short* A_l, const unsigned short* wt,
                                          int colbase, int l15, int l4, f32x4 acc[4][4]) {
    f32x4 zf = {0.f, 0.f, 0.f, 0.f};
#pragma unroll
    for (int a = 0; a < 4; a++)
#pragma unroll
        for (int b = 0; b < 4; b++) acc[a][b] = zf;
    for (int ks = 0; ks < 8; ks++) {
        int k0 = ks * 32;
        short8 af[4], bfr[4];
#pragma unroll
        for (int rb = 0; rb < 4; rb++)
            af[rb] = *(const short8*)(A_l + (rb * 16 + l15) * LDA + k0 + 8 * l4);
#pragma unroll
        for (int cb = 0; cb < 4; cb++)
            bfr[cb] = *(const short8*)(wt + (size_t)(colbase + cb * 16 + l15) * 256 + k0 + 8 * l4);
#pragma unroll
        for (int rb = 0; rb < 4; rb++)
#pragma unroll
            for (int cb = 0; cb < 4; cb++)
                acc[rb][cb] = __builtin_amdgcn_mfma_f32_16x16x32_bf16(af[rb], bfr[cb], acc[rb][cb], 0, 0, 0);
    }
}

// MODE 0: tanh epilogue -> bf16
// MODE 2: bias + skip-blend (x_in bf16) + LayerNorm -> bf16 (+f32 if out_f32)
template <int MODE>
__global__ __launch_bounds__(256) void k_gemm(
    const unsigned short* __restrict__ Abf,
    const unsigned short* __restrict__ Wt,
    const float* __restrict__ bias,
    const int* __restrict__ nlist, const int* __restrict__ toff,
    unsigned short* __restrict__ out_bf, float* out_f32,
    const unsigned short* x_in, const float* __restrict__ skipv,
    const float* __restrict__ lng, const float* __restrict__ lnb)
{
    __shared__ unsigned short A_l[64 * LDA];
    __shared__ int nid[64];
    __shared__ float redS[64 * 4];
    __shared__ float redQ[64 * 4];
    __shared__ float meanl[64];
    __shared__ float invl[64];

    int t = blockIdx.y;
    int g0 = toff[t], g1 = toff[t + 1];
    int base = blockIdx.x * 64;
    int cnt = g1 - g0 - base;
    if (cnt <= 0) return;
    if (cnt > 64) cnt = 64;
    int tid = threadIdx.x;
    if (tid < 64) nid[tid] = (tid < cnt) ? nlist[g0 + base + tid] : -1;
    __syncthreads();

#pragma unroll
    for (int it = 0; it < 8; it++) {
        int id = it * 256 + tid;
        int row = id >> 5, c8 = id & 31;
        short8 v = {};
        int nd = nid[row];
        if (nd >= 0) v = *(const short8*)(Abf + (size_t)nd * 256 + c8 * 8);
        *(short8*)(A_l + row * LDA + c8 * 8) = v;
    }
    __syncthreads();

    int lane = tid & 63, wave = tid >> 6;
    int colbase = wave * 64;
    int l15 = lane & 15, l4 = lane >> 4;
    f32x4 acc[4][4];
    gemm_core(A_l, Wt + (size_t)t * 65536, colbase, l15, l4, acc);

    if (MODE == 0) {
#pragma unroll
        for (int rb = 0; rb < 4; rb++) {
#pragma unroll
            for (int j = 0; j < 4; j++) {
                int r = rb * 16 + l4 * 4 + j;
                int nd = nid[r];
                if (nd < 0) continue;
#pragma unroll
                for (int cb = 0; cb < 4; cb++) {
                    int col = colbase + cb * 16 + l15;
                    float v = tanhf(acc[rb][cb][j] + bias[t * 256 + col]);
                    out_bf[(size_t)nd * 256 + col] = f2b(v);
                }
            }
        }
    } else {
        float alpha = 1.f / (1.f + __expf(-skipv[t]));
#pragma unroll
        for (int rb = 0; rb < 4; rb++) {
#pragma unroll
            for (int j = 0; j < 4; j++) {
                int r = rb * 16 + l4 * 4 + j;
                int nd = nid[r];
                float s = 0.f, q = 0.f;
#pragma unroll
                for (int cb = 0; cb < 4; cb++) {
                    int col = colbase + cb * 16 + l15;
                    float v = acc[rb][cb][j] + bias[t * 256 + col];
                    float xi = (nd >= 0) ? b2f(x_in[(size_t)nd * 256 + col]) : 0.f;
                    float o = v * alpha + xi * (1.f - alpha);
                    acc[rb][cb][j] = o;
                    s += o;
                    q += o * o;
                }
#pragma unroll
                for (int m = 1; m < 16; m <<= 1) {
                    s += __shfl_xor(s, m, 16);
                    q += __shfl_xor(q, m, 16);
                }
                if (l15 == 0) { redS[r * 4 + wave] = s; redQ[r * 4 + wave] = q; }
            }
        }
        __syncthreads();
        if (tid < 64) {
            float s = redS[tid * 4] + redS[tid * 4 + 1] + redS[tid * 4 + 2] + redS[tid * 4 + 3];
            float q = redQ[tid * 4] + redQ[tid * 4 + 1] + redQ[tid * 4 + 2] + redQ[tid * 4 + 3];
            float mean = s * (1.f / 256.f);
            float var = q * (1.f / 256.f) - mean * mean;
            meanl[tid] = mean;
            invl[tid] = rsqrtf(var + 1e-5f);
        }
        __syncthreads();
#pragma unroll
        for (int rb = 0; rb < 4; rb++) {
#pragma unroll
            for (int j = 0; j < 4; j++) {
                int r = rb * 16 + l4 * 4 + j;
                int nd = nid[r];
                if (nd < 0) continue;
                float mean = meanl[r], inv = invl[r];
#pragma unroll
                for (int cb = 0; cb < 4; cb++) {
                    int col = colbase + cb * 16 + l15;
                    float o = (acc[rb][cb][j] - mean) * inv * lng[t * 256 + col] + lnb[t * 256 + col];
                    if (out_f32) out_f32[(size_t)nd * 256 + col] = o;
                    out_bf[(size_t)nd * 256 + col] = f2b(o);
                }
            }
        }
    }
}

// fused k/q/v: stage A once, run 3 weight sets
__global__ __launch_bounds__(256) void k_gemm3(
    const unsigned short* __restrict__ Abf,
    const unsigned short* __restrict__ Wt0, const unsigned short* __restrict__ Wt1,
    const unsigned short* __restrict__ Wt2,
    const float* __restrict__ b0, const float* __restrict__ b1, const float* __restrict__ b2,
    const int* __restrict__ nlist, const int* __restrict__ toff,
    unsigned short* __restrict__ o0, unsigned short* __restrict__ o1,
    unsigned short* __restrict__ o2)
{
    __shared__ unsigned short A_l[64 * LDA];
    __shared__ int nid[64];

    int t = blockIdx.y;
    int g0 = toff[t], g1 = toff[t + 1];
    int base = blockIdx.x * 64;
    int cnt = g1 - g0 - base;
    if (cnt <= 0) return;
    if (cnt > 64) cnt = 64;
    int tid = threadIdx.x;
    if (tid < 64) nid[tid] = (tid < cnt) ? nlist[g0 + base + tid] : -1;
    __syncthreads();

#pragma unroll
    for (int it = 0; it < 8; it++) {
        int id = it * 256 + tid;
        int row = id >> 5, c8 = id & 31;
        short8 v = {};
        int nd = nid[row];
        if (nd >= 0) v = *(const short8*)(Abf + (size_t)nd * 256 + c8 * 8);
        *(short8*)(A_l + row * LDA + c8 * 8) = v;
    }
    __syncthreads();

    int lane = tid & 63, wave = tid >> 6;
    int colbase = wave * 64;
    int l15 = lane & 15, l4 = lane >> 4;
    const unsigned short* Wts[3] = {Wt0, Wt1, Wt2};
    const float* bs[3] = {b0, b1, b2};
    unsigned short* os[3] = {o0, o1, o2};
#pragma unroll
    for (int w = 0; w < 3; w++) {
        f32x4 acc[4][4];
        gemm_core(A_l, Wts[w] + (size_t)t * 65536, colbase, l15, l4, acc);
#pragma unroll
        for (int rb = 0; rb < 4; rb++) {
#pragma unroll
            for (int j = 0; j < 4; j++) {
                int r = rb * 16 + l4 * 4 + j;
                int nd = nid[r];
                if (nd < 0) continue;
#pragma unroll
                for (int cb = 0; cb < 4; cb++) {
                    int col = colbase + cb * 16 + l15;
                    os[w][(size_t)nd * 256 + col] = f2b(acc[rb][cb][j] + bs[w][t * 256 + col]);
                }
            }
        }
    }
}

// ---------- q-side relation transform: rh-major [R*H][N][32], contiguous writes ----------
__global__ __launch_bounds__(256) void k_rtq(
    const unsigned short* __restrict__ qb,
    const unsigned short* __restrict__ relA,
    unsigned short* __restrict__ qrt)
{
    int tid = threadIdx.x;
    int lane = tid & 63, wave = tid >> 6;
    int l15 = lane & 15, l4 = lane >> 4;
    int h = blockIdx.y;
    int n = blockIdx.x * 64 + wave * 16 + l15;
    bool ok = (n < NN);
    short8 bfrag = {};
    if (ok) bfrag = *(const short8*)(qb + (size_t)n * 256 + h * 32 + 8 * l4);
#pragma unroll
    for (int r = 0; r < RR; r++) {
        const unsigned short* ap = relA + ((size_t)(r * HH + h)) * 1024;
        short8 a0 = *(const short8*)(ap + l15 * 32 + 8 * l4);
        short8 a1 = *(const short8*)(ap + (16 + l15) * 32 + 8 * l4);
        f32x4 c0 = {0.f, 0.f, 0.f, 0.f}, c1 = {0.f, 0.f, 0.f, 0.f};
        c0 = __builtin_amdgcn_mfma_f32_16x16x32_bf16(a0, bfrag, c0, 0, 0, 0);
        c1 = __builtin_amdgcn_mfma_f32_16x16x32_bf16(a1, bfrag, c1, 0, 0, 0);
        if (ok) {
            size_t ob = (((size_t)(r * HH + h)) * NN + n) * 32;
            us4 p0, p1;
#pragma unroll
            for (int j = 0; j < 4; j++) { p0[j] = f2b(c0[j]); p1[j] = f2b(c1[j]); }
            *(us4*)(qrt + ob + l4 * 4) = p0;
            *(us4*)(qrt + ob + 16 + l4 * 4) = p1;
        }
    }
}

// ---------- v-side relation transform: node-major [N][R*H][32], LDS-staged ----------
// vb fragments cached in registers (vb read ONCE); per r: 8 h MFMAs -> packed us8
// into padded wave-private LDS; flush as 1KB-contiguous stores (2 adjacent nodes
// x 512B per instruction). Element order inside each 64B block identical to
// round-12 (consumer k_agg's dg/ob mapping unchanged).
#define VSTRIDE 33   // us8 units per node (8h*4l4 + 1 pad) -> <=2-way LDS aliasing
__global__ __launch_bounds__(256) void k_rtv(
    const unsigned short* __restrict__ vb,
    const unsigned short* __restrict__ relMT,
    unsigned short* __restrict__ vrt)
{
    __shared__ us8 stg[4][16][VSTRIDE];
    int tid = threadIdx.x;
    int lane = tid & 63, wave = tid >> 6;
    int l15 = lane & 15, l4 = lane >> 4;
    int nbase = blockIdx.x * 64 + wave * 16;
    int n = nbase + l15;
    bool ok = (n < NN);
    short8 bfrag[8];
#pragma unroll
    for (int h = 0; h < HH; h++) {
        short8 z = {};
        bfrag[h] = ok ? *(const short8*)(vb + (size_t)n * 256 + h * 32 + 8 * l4) : z;
    }
    int nodeHalf = lane >> 5;    // 0/1
    int unit = lane & 31;        // 32 x us8 = 512B per node
    for (int r = 0; r < RR; r++) {
#pragma unroll
        for (int h = 0; h < HH; h++) {
            const unsigned short* ap = relMT + ((size_t)(r * HH + h)) * 1024;
            short8 a0 = *(const short8*)(ap + l15 * 32 + 8 * l4);
            short8 a1 = *(const short8*)(ap + (16 + l15) * 32 + 8 * l4);
            f32x4 c0 = {0.f, 0.f, 0.f, 0.f}, c1 = {0.f, 0.f, 0.f, 0.f};
            c0 = __builtin_amdgcn_mfma_f32_16x16x32_bf16(a0, bfrag[h], c0, 0, 0, 0);
            c1 = __builtin_amdgcn_mfma_f32_16x16x32_bf16(a1, bfrag[h], c1, 0, 0, 0);
            us8 pk;
#pragma unroll
            for (int j = 0; j < 4; j++) { pk[j] = f2b(c0[j]); pk[4 + j] = f2b(c1[j]); }
            stg[wave][l15][h * 4 + l4] = pk;   // wave-private; no barrier needed
        }
        // flush: 8 iterations x (2 adjacent nodes x 512B) = 1KB contiguous/instr
#pragma unroll
        for (int f = 0; f < 8; f++) {
            int node = f * 2 + nodeHalf;
            us8 v = stg[wave][node][unit];
            int gn = nbase + node;
            if (gn < NN)
                *(us8*)(vrt + (size_t)gn * 2048 + r * 256 + unit * 8) = v;
        }
    }
}

// ---------- edge scores over CSR positions (coalesced writes) ----------
__global__ void k_score(const unsigned short* __restrict__ kbf,
                        const unsigned short* __restrict__ qrt,
                        const int4* __restrict__ csr, const float* __restrict__ pri,
                        float* __restrict__ sc)
{
    int idx = blockIdx.x * 256 + threadIdx.x;
    if (idx >= EE * HH) return;
    int p = idx >> 3, h = idx & 7;
    int4 pk = csr[p];
    int s = pk.x & 0xffff, r = (pk.x >> 16) & 7;
    float w = __int_as_float(pk.y);
    int d = pk.z;
    const short8* kp = (const short8*)(kbf + (size_t)s * 256 + h * 32);
    const short8* qp = (const short8*)(qrt + (((size_t)(r * HH + h)) * NN + d) * 32);
    float acc = 0.f;
#pragma unroll
    for (int c = 0; c < 4; c++) {
        short8 a = kp[c], b = qp[c];
#pragma unroll
        for (int j = 0; j < 8; j++)
            acc += b2f((unsigned short)a[j]) * b2f((unsigned short)b[j]);
    }
    sc[idx] = acc * pri[r * HH + h] * 0.17677669529663687f * w;
}

// ---------- per-dst softmax + aggregate + gelu ----------
// lanes of each h-group: (sp = i>>3) slot-phase, (dg = i&7) dim-group.
// Each lane reads us4 (8B) of the 64B vrt block; 4 independent slot chains.
__global__ __launch_bounds__(256) void k_agg(
    const float* __restrict__ sc, const unsigned short* __restrict__ vrt,
    const int4* __restrict__ csr, const int* __restrict__ off,
    unsigned short* __restrict__ gbf, float* __restrict__ smaxg, float* __restrict__ ssumg)
{
    __shared__ float p_l[32][9];
    __shared__ int sbase[32];     // (src*64 + et*8)*32 ushort index base
    int n = blockIdx.x;
    int tid = threadIdx.x;
    int h = tid >> 5, i = tid & 31;
    int sp = i >> 3, dg = i & 7;
    int ob = ((dg & 1) << 4) | (((dg >> 2) & 1) << 3) | (((dg >> 1) & 1) << 2);
    int t0 = off[n], cnt = off[n + 1] - t0;
    int hoff = h * 32 + dg * 4;   // thread-constant offset inside node's 2048-elem region

    float smax = -INFINITY;
    for (int ii = i; ii < cnt; ii += 32)
        smax = fmaxf(smax, sc[(size_t)(t0 + ii) * 8 + h]);
#pragma unroll
    for (int m = 16; m >= 1; m >>= 1) smax = fmaxf(smax, __shfl_xor(smax, m, 32));

    float psum = 0.f;
    float a0 = 0.f, a1 = 0.f, a2 = 0.f, a3 = 0.f;
    for (int c0 = 0; c0 < cnt; c0 += 32) {
        int m = cnt - c0;
        if (m > 32) m = 32;
        __syncthreads();
        if (tid < m) {
            int4 pk = csr[t0 + c0 + tid];
            sbase[tid] = ((pk.x & 0xffff) * 64 + ((pk.x >> 16) & 7) * 8) * 32;
        }
        __syncthreads();
        if (i < m) {
            float p = __expf(sc[(size_t)(t0 + c0 + i) * 8 + h] - smax);
            p_l[i][h] = p;
            psum += p;
        }
        // no barrier: producer/consumer of p_l[.][h]/sbase share a 32-lane group
        for (int ii = sp; ii < m; ii += 4) {
            float p = p_l[ii][h];
            us4 v = *(const us4*)(vrt + (size_t)(unsigned)sbase[ii] + hoff);
            a0 = fmaf(p, b2f(v[0]), a0);
            a1 = fmaf(p, b2f(v[1]), a1);
            a2 = fmaf(p, b2f(v[2]), a2);
            a3 = fmaf(p, b2f(v[3]), a3);
        }
    }
#pragma unroll
    for (int m = 16; m >= 1; m >>= 1) psum += __shfl_xor(psum, m, 32);
    // merge the 4 slot-phases (lane bits 3,4)
#pragma unroll
    for (int m = 8; m <= 16; m <<= 1) {
        a0 += __shfl_xor(a0, m, 32);
        a1 += __shfl_xor(a1, m, 32);
        a2 += __shfl_xor(a2, m, 32);
        a3 += __shfl_xor(a3, m, 32);
    }
    if (i == 0) { smaxg[n * 8 + h] = smax; ssumg[n * 8 + h] = psum; }
    float den = psum + 1e-9f;
    float av = (sp == 0) ? a0 : (sp == 1) ? a1 : (sp == 2) ? a2 : a3;
    float a = av / den;
    float g = 0.5f * a * (1.f + tanhf(0.7978845608028654f * (a + 0.044715f * a * a * a)));
    gbf[(size_t)n * 256 + h * 32 + ob + sp] = f2b(g);
}

// ---------- attention output over CSR positions (last layer) ----------
__global__ void k_att(const float* __restrict__ sc, const int4* __restrict__ csr,
                      const float* __restrict__ smaxg, const float* __restrict__ ssumg,
                      float* __restrict__ att)
{
    int idx = blockIdx.x * 256 + threadIdx.x;
    if (idx >= EE * HH) return;
    int p = idx >> 3, h = idx & 7;
    int4 pk = csr[p];
    int d = pk.z, e = pk.w;
    att[(size_t)e * 8 + h] = __expf(sc[idx] - smaxg[d * 8 + h]) / (ssumg[d * 8 + h] + 1e-9f);
}

extern "C" void kernel_launch(void* const* d_in, const int* in_sizes, int n_in,
                              void* d_out, int out_size, void* d_ws, size_t ws_size,
                              hipStream_t stream)
{
    const float* nf = (const float*)d_in[0];
    const int* ntyp = (const int*)d_in[1];
    const float* ew = (const float*)d_in[2];
    const int* ei = (const int*)d_in[3];
    const int* ety = (const int*)d_in[4];
    const float* adW = (const float*)d_in[5];
    const float* adb = (const float*)d_in[6];
    const float* kW = (const float*)d_in[7];
    const float* kb = (const float*)d_in[8];
    const float* qW = (const float*)d_in[9];
    const float* qb = (const float*)d_in[10];
    const float* vW = (const float*)d_in[11];
    const float* vb = (const float*)d_in[12];
    const float* aW = (const float*)d_in[13];
    const float* ab = (const float*)d_in[14];
    const float* pri = (const float*)d_in[15];
    const float* rA = (const float*)d_in[16];
    const float* rM = (const float*)d_in[17];
    const float* skp = (const float*)d_in[18];
    const float* lng = (const float*)d_in[19];
    const float* lnb = (const float*)d_in[20];

    float* x_out = (float*)d_out;
    float* att_out = x_out + (size_t)NN * 256;

    char* wsb = (char*)d_ws;
    size_t o = 0;
    auto take = [&](size_t bytes) -> void* {
        size_t r = (o + 255) & ~(size_t)255;
        o = r + bytes;
        return (void*)(wsb + r);
    };
    unsigned short* nf_bf = (unsigned short*)take((size_t)NN * 256 * 2);
    unsigned short* x_bf = (unsigned short*)take((size_t)NN * 256 * 2);
    unsigned short* kb16 = (unsigned short*)take((size_t)NN * 256 * 2);
    unsigned short* qb16 = (unsigned short*)take((size_t)NN * 256 * 2);
    unsigned short* vb16 = (unsigned short*)take((size_t)NN * 256 * 2);
    unsigned short* gb16 = (unsigned short*)take((size_t)NN * 256 * 2);
    unsigned short* qrt = (unsigned short*)take((size_t)NN * RR * HH * 32 * 2);
    unsigned short* vrt = (unsigned short*)take((size_t)NN * RR * HH * 32 * 2);
    float* scores = (float*)take((size_t)EE * HH * 4);
    float* smaxg = (float*)take((size_t)NN * HH * 4);
    float* ssumg = (float*)take((size_t)NN * HH * 4);
    unsigned short* Wt_all = (unsigned short*)take((size_t)72 * 65536 * 2);
    unsigned short* adWt = Wt_all;
    unsigned short* kWt = Wt_all + (size_t)8 * 65536;
    unsigned short* qWt = Wt_all + (size_t)24 * 65536;
    unsigned short* vWt = Wt_all + (size_t)40 * 65536;
    unsigned short* aWt = Wt_all + (size_t)56 * 65536;
    unsigned short* relA = (unsigned short*)take((size_t)RELN * 2);
    unsigned short* relMT = (unsigned short*)take((size_t)RELN * 2);
    // zero block: deg8 (8*NN) + thist (NBN*TT)
    int* zblock = (int*)take((size_t)(8 * NN + NBN * TT) * 4);
    int* deg8 = zblock;
    int* thist = zblock + 8 * NN;
    int* base8 = (int*)take((size_t)8 * NN * 4);
    int* degT = (int*)take((size_t)NN * 4);
    int* bsum = (int*)take((size_t)NBN * 4);
    int* bbase = (int*)take((size_t)NBN * 4);
    int* rank = (int*)take((size_t)EE * 4);
    int* off = (int*)take((size_t)(NN + 1) * 4);
    int4* csr = (int4*)take((size_t)EE * 16);
    int* tboff = (int*)take((size_t)NBN * TT * 4);
    int* toff = (int*)take((TT + 1) * 4);
    int* nlist = (int*)take((size_t)NN * 4);
    if (o > ws_size) return;  // workspace insufficient — fail visibly

    hipMemsetAsync(zblock, 0, (size_t)(8 * NN + NBN * TT) * 4, stream);

    int ptot = NN * 256 + 2 * RELN;
    k_prep<<<(ptot + 255) / 256, 256, 0, stream>>>(nf, rA, rM, nf_bf, relA, relMT);
    k_transpose_all<<<dim3(8, 8, 72), dim3(32, 8), 0, stream>>>(adW, kW, qW, vW, aW, Wt_all);

    k_build1<<<(EE + 255) / 256, 256, 0, stream>>>(ei, ntyp, deg8, thist, rank);
    k_scanA<<<NBN, 256, 0, stream>>>(deg8, degT, bsum);
    k_scanB<<<1, 256, 0, stream>>>(bsum, bbase, off, thist, toff, tboff);
    k_scanC<<<NBN, 256, 0, stream>>>(deg8, degT, bbase, off, base8);
    k_build2<<<(EE + 255) / 256, 256, 0, stream>>>(ei, ety, ew, ntyp, base8, tboff, rank,
                                                   csr, nlist);

    dim3 ggrid((NN + 63) / 64, TT);
    k_gemm<0><<<ggrid, 256, 0, stream>>>(nf_bf, adWt, adb, nlist, toff,
                                         x_bf, nullptr, nullptr, nullptr, nullptr, nullptr);

    dim3 rgridq((NN + 63) / 64, HH);
    int rgridv = (NN + 63) / 64;
    int egrid = (EE * HH + 255) / 256;
    for (int l = 0; l < LLAYERS; l++) {
        k_gemm3<<<ggrid, 256, 0, stream>>>(x_bf,
                                           kWt + (size_t)l * TT * 65536, qWt + (size_t)l * TT * 65536,
                                           vWt + (size_t)l * TT * 65536,
                                           kb + (size_t)l * TT * 256, qb + (size_t)l * TT * 256,
                                           vb + (size_t)l * TT * 256,
                                           nlist, toff, kb16, qb16, vb16);
        k_rtq<<<rgridq, 256, 0, stream>>>(qb16, relA + (size_t)l * RR * HH * 1024, qrt);
        k_rtv<<<rgridv, 256, 0, stream>>>(vb16, relMT + (size_t)l * RR * HH * 1024, vrt);
        k_score<<<egrid, 256, 0, stream>>>(kb16, qrt, csr, pri + (size_t)l * RR * HH, scores);
        k_agg<<<NN, 256, 0, stream>>>(scores, vrt, csr, off, gb16, smaxg, ssumg);
        if (l == LLAYERS - 1)
            k_att<<<egrid, 256, 0, stream>>>(scores, csr, smaxg, ssumg, att_out);
        k_gemm<2><<<ggrid, 256, 0, stream>>>(gb16, aWt + (size_t)l * TT * 65536, ab + (size_t)l * TT * 256,
                                             nlist, toff, x_bf,
                                             (l == LLAYERS - 1) ? x_out : nullptr,
                                             x_bf,
                                             skp + (size_t)l * TT, lng + (size_t)l * TT * 256, lnb + (size_t)l * TT * 256);
    }
}

// Round 14
// 533.136 us; speedup vs baseline: 1.0496x; 1.0496x over previous
//
#include <hip/hip_runtime.h>
#include <hip/hip_bf16.h>
#include <math.h>

#define NN 20000
#define EE 320000
#define DD 256
#define TT 8
#define RR 8
#define HH 8
#define LLAYERS 2
#define RELN (LLAYERS * RR * HH * 1024)
#define NBN 79   // node blocks (79*256 >= 20000)

typedef __attribute__((ext_vector_type(8))) short short8;
typedef __attribute__((ext_vector_type(4))) float f32x4;
typedef __attribute__((ext_vector_type(4))) unsigned short us4;
typedef __attribute__((ext_vector_type(8))) unsigned short us8;

__device__ __forceinline__ float b2f(unsigned short u) {
    return __uint_as_float(((unsigned int)u) << 16);
}
__device__ __forceinline__ unsigned short f2b(float f) {
    unsigned int x = __float_as_uint(f);
    unsigned int r = (x + 0x7fffu + ((x >> 16) & 1u)) >> 16;
    return (unsigned short)r;
}

// ---------- one-shot prep: nf conv + relA conv + relM transposed conv ----------
__global__ void k_prep(const float* __restrict__ nf, const float* __restrict__ rA,
                       const float* __restrict__ rM,
                       unsigned short* __restrict__ nf_bf, unsigned short* __restrict__ relA,
                       unsigned short* __restrict__ relMT) {
    int idx = blockIdx.x * 256 + threadIdx.x;
    const int n0 = NN * 256;
    if (idx < n0) { nf_bf[idx] = f2b(nf[idx]); return; }
    idx -= n0;
    if (idx < RELN) { relA[idx] = f2b(rA[idx]); return; }
    idx -= RELN;
    if (idx < RELN) {
        int g = idx >> 10, loc = idx & 1023;
        int a = loc >> 5, b = loc & 31;
        // relMT[g][e][d] = rM[g][d][e]  (32x32 block transpose)
        relMT[(size_t)g * 1024 + a * 32 + b] = f2b(rM[(size_t)g * 1024 + b * 32 + a]);
    }
}

// ---------- all weight transposes in one kernel ----------
__global__ void k_transpose_all(const float* __restrict__ adW, const float* __restrict__ kW,
                                const float* __restrict__ qW, const float* __restrict__ vW,
                                const float* __restrict__ aW, unsigned short* __restrict__ out) {
    __shared__ float tile[32][33];
    int z = blockIdx.z;
    const float* ip;
    if (z < 8) ip = adW + (size_t)z * 65536;
    else if (z < 24) ip = kW + (size_t)(z - 8) * 65536;
    else if (z < 40) ip = qW + (size_t)(z - 24) * 65536;
    else if (z < 56) ip = vW + (size_t)(z - 40) * 65536;
    else ip = aW + (size_t)(z - 56) * 65536;
    unsigned short* op = out + (size_t)z * 65536;
    int ox = blockIdx.x * 32, dy = blockIdx.y * 32;
    int tx = threadIdx.x, ty = threadIdx.y; // 32 x 8
#pragma unroll
    for (int r = 0; r < 4; r++) tile[ty + 8 * r][tx] = ip[(size_t)(dy + ty + 8 * r) * 256 + ox + tx];
    __syncthreads();
#pragma unroll
    for (int r = 0; r < 4; r++) op[(size_t)(ox + ty + 8 * r) * 256 + dy + tx] = f2b(tile[tx][ty + 8 * r]);
}

// ---------- graph build ----------
__global__ void k_build1(const int* __restrict__ ei, const int* __restrict__ nt,
                         int* __restrict__ deg8, int* __restrict__ thist,
                         int* __restrict__ rank) {
    __shared__ int ltc[TT];
    int i = blockIdx.x * 256 + threadIdx.x;
    int vx = blockIdx.x & 7;
    if (i < EE) {
        int d = ei[EE + i];
        int lr = atomicAdd(&deg8[vx * NN + d], 1);
        rank[i] = (vx << 16) | lr;
    }
    if (blockIdx.x < NBN) {
        if (threadIdx.x < TT) ltc[threadIdx.x] = 0;
        __syncthreads();
        int n = blockIdx.x * 256 + threadIdx.x;
        if (n < NN) atomicAdd(&ltc[nt[n]], 1);
        __syncthreads();
        if (threadIdx.x < TT) thist[blockIdx.x * TT + threadIdx.x] = ltc[threadIdx.x];
    }
}

__global__ __launch_bounds__(256) void k_scanA(const int* __restrict__ deg8,
                                               int* __restrict__ degT,
                                               int* __restrict__ bsum) {
    __shared__ int red[256];
    int b = blockIdx.x, t = threadIdx.x;
    int n = b * 256 + t;
    int tot = 0;
    if (n < NN) {
#pragma unroll
        for (int vx = 0; vx < 8; vx++) tot += deg8[vx * NN + n];
        degT[n] = tot;
    }
    red[t] = tot;
    __syncthreads();
    for (int d = 128; d >= 1; d >>= 1) {
        if (t < d) red[t] += red[t + d];
        __syncthreads();
    }
    if (t == 0) bsum[b] = red[0];
}

__global__ void k_scanB(const int* __restrict__ bsum, int* __restrict__ bbase,
                        int* __restrict__ off,
                        const int* __restrict__ thist, int* __restrict__ toff,
                        int* __restrict__ tboff) {
    __shared__ int partial[TT];
    __shared__ int toff_l[TT + 1];
    int tid = threadIdx.x;
    if (tid == 0) {
        int a = 0;
        for (int b = 0; b < NBN; b++) { bbase[b] = a; a += bsum[b]; }
        off[NN] = EE;
    }
    if (tid < TT) {
        int tot = 0;
        for (int b = 0; b < NBN; b++) tot += thist[b * TT + tid];
        partial[tid] = tot;
    }
    __syncthreads();
    if (tid == 0) {
        int a = 0;
        for (int t = 0; t < TT; t++) { toff_l[t] = a; toff[t] = a; a += partial[t]; }
        toff_l[TT] = a; toff[TT] = a;
    }
    __syncthreads();
    if (tid < TT) {
        int r = toff_l[tid];
        for (int b = 0; b < NBN; b++) { tboff[b * TT + tid] = r; r += thist[b * TT + tid]; }
    }
}

__global__ __launch_bounds__(256) void k_scanC(const int* __restrict__ deg8,
                                               const int* __restrict__ degT,
                                               const int* __restrict__ bbase,
                                               int* __restrict__ off,
                                               int* __restrict__ base8) {
    __shared__ int s[256];
    int b = blockIdx.x, t = threadIdx.x;
    int n = b * 256 + t;
    int v = (n < NN) ? degT[n] : 0;
    s[t] = v;
    __syncthreads();
    for (int d = 1; d < 256; d <<= 1) {
        int x = (t >= d) ? s[t - d] : 0;
        __syncthreads();
        s[t] += x;
        __syncthreads();
    }
    if (n < NN) {
        int run = bbase[b] + s[t] - v;   // exclusive prefix
        off[n] = run;
#pragma unroll
        for (int vx = 0; vx < 8; vx++) {
            base8[vx * NN + n] = run;
            run += deg8[vx * NN + n];
        }
    }
}

// atomic-free CSR fill (one packed 16B scatter/edge) + atomic-free nlist
__global__ void k_build2(const int* __restrict__ ei, const int* __restrict__ et,
                         const float* __restrict__ ew, const int* __restrict__ nt,
                         const int* __restrict__ base8, const int* __restrict__ tboff,
                         const int* __restrict__ rank,
                         int4* __restrict__ csr, int* __restrict__ nlist) {
    __shared__ int ltc[TT];
    int i = blockIdx.x * 256 + threadIdx.x;
    if (i < EE) {
        int d = ei[EE + i];
        int rk = rank[i];
        int p = base8[(rk >> 16) * NN + d] + (rk & 0xffff);
        int4 pk;
        pk.x = ei[i] | (et[i] << 16);
        pk.y = __float_as_int(ew[i]);
        pk.z = d;
        pk.w = i;
        csr[p] = pk;
    }
    if (blockIdx.x < NBN) {
        if (threadIdx.x < TT) ltc[threadIdx.x] = 0;
        __syncthreads();
        int n = blockIdx.x * 256 + threadIdx.x;
        if (n < NN) {
            int t = nt[n];
            int pos = atomicAdd(&ltc[t], 1);
            nlist[tboff[blockIdx.x * TT + t] + pos] = n;
        }
    }
}

// ---------- type-grouped GEMM (64 rows x 256 cols, K=256) ----------
#define LDA 264

__device__ __forceinline__ void gemm_core(const unsigned short* A_l, const unsigned short* wt,
                                          int colbase, int l15, int l4, f32x4 acc[4][4]) {
    f32x4 zf = {0.f, 0.f, 0.f, 0.f};
#pragma unroll
    for (int a = 0; a < 4; a++)
#pragma unroll
        for (int b = 0; b < 4; b++) acc[a][b] = zf;
    for (int ks = 0; ks < 8; ks++) {
        int k0 = ks * 32;
        short8 af[4], bfr[4];
#pragma unroll
        for (int rb = 0; rb < 4; rb++)
            af[rb] = *(const short8*)(A_l + (rb * 16 + l15) * LDA + k0 + 8 * l4);
#pragma unroll
        for (int cb = 0; cb < 4; cb++)
            bfr[cb] = *(const short8*)(wt + (size_t)(colbase + cb * 16 + l15) * 256 + k0 + 8 * l4);
#pragma unroll
        for (int rb = 0; rb < 4; rb++)
#pragma unroll
            for (int cb = 0; cb < 4; cb++)
                acc[rb][cb] = __builtin_amdgcn_mfma_f32_16x16x32_bf16(af[rb], bfr[cb], acc[rb][cb], 0, 0, 0);
    }
}

// MODE 0: tanh epilogue -> bf16
// MODE 2: bias + skip-blend (x_in bf16) + LayerNorm -> bf16 (+f32 if out_f32)
template <int MODE>
__global__ __launch_bounds__(256) void k_gemm(
    const unsigned short* __restrict__ Abf,
    const unsigned short* __restrict__ Wt,
    const float* __restrict__ bias,
    const int* __restrict__ nlist, const int* __restrict__ toff,
    unsigned short* __restrict__ out_bf, float* out_f32,
    const unsigned short* x_in, const float* __restrict__ skipv,
    const float* __restrict__ lng, const float* __restrict__ lnb)
{
    __shared__ unsigned short A_l[64 * LDA];
    __shared__ int nid[64];
    __shared__ float redS[64 * 4];
    __shared__ float redQ[64 * 4];
    __shared__ float meanl[64];
    __shared__ float invl[64];

    int t = blockIdx.y;
    int g0 = toff[t], g1 = toff[t + 1];
    int base = blockIdx.x * 64;
    int cnt = g1 - g0 - base;
    if (cnt <= 0) return;
    if (cnt > 64) cnt = 64;
    int tid = threadIdx.x;
    if (tid < 64) nid[tid] = (tid < cnt) ? nlist[g0 + base + tid] : -1;
    __syncthreads();

#pragma unroll
    for (int it = 0; it < 8; it++) {
        int id = it * 256 + tid;
        int row = id >> 5, c8 = id & 31;
        short8 v = {};
        int nd = nid[row];
        if (nd >= 0) v = *(const short8*)(Abf + (size_t)nd * 256 + c8 * 8);
        *(short8*)(A_l + row * LDA + c8 * 8) = v;
    }
    __syncthreads();

    int lane = tid & 63, wave = tid >> 6;
    int colbase = wave * 64;
    int l15 = lane & 15, l4 = lane >> 4;
    f32x4 acc[4][4];
    gemm_core(A_l, Wt + (size_t)t * 65536, colbase, l15, l4, acc);

    if (MODE == 0) {
#pragma unroll
        for (int rb = 0; rb < 4; rb++) {
#pragma unroll
            for (int j = 0; j < 4; j++) {
                int r = rb * 16 + l4 * 4 + j;
                int nd = nid[r];
                if (nd < 0) continue;
#pragma unroll
                for (int cb = 0; cb < 4; cb++) {
                    int col = colbase + cb * 16 + l15;
                    float v = tanhf(acc[rb][cb][j] + bias[t * 256 + col]);
                    out_bf[(size_t)nd * 256 + col] = f2b(v);
                }
            }
        }
    } else {
        float alpha = 1.f / (1.f + __expf(-skipv[t]));
#pragma unroll
        for (int rb = 0; rb < 4; rb++) {
#pragma unroll
            for (int j = 0; j < 4; j++) {
                int r = rb * 16 + l4 * 4 + j;
                int nd = nid[r];
                float s = 0.f, q = 0.f;
#pragma unroll
                for (int cb = 0; cb < 4; cb++) {
                    int col = colbase + cb * 16 + l15;
                    float v = acc[rb][cb][j] + bias[t * 256 + col];
                    float xi = (nd >= 0) ? b2f(x_in[(size_t)nd * 256 + col]) : 0.f;
                    float o = v * alpha + xi * (1.f - alpha);
                    acc[rb][cb][j] = o;
                    s += o;
                    q += o * o;
                }
#pragma unroll
                for (int m = 1; m < 16; m <<= 1) {
                    s += __shfl_xor(s, m, 16);
                    q += __shfl_xor(q, m, 16);
                }
                if (l15 == 0) { redS[r * 4 + wave] = s; redQ[r * 4 + wave] = q; }
            }
        }
        __syncthreads();
        if (tid < 64) {
            float s = redS[tid * 4] + redS[tid * 4 + 1] + redS[tid * 4 + 2] + redS[tid * 4 + 3];
            float q = redQ[tid * 4] + redQ[tid * 4 + 1] + redQ[tid * 4 + 2] + redQ[tid * 4 + 3];
            float mean = s * (1.f / 256.f);
            float var = q * (1.f / 256.f) - mean * mean;
            meanl[tid] = mean;
            invl[tid] = rsqrtf(var + 1e-5f);
        }
        __syncthreads();
#pragma unroll
        for (int rb = 0; rb < 4; rb++) {
#pragma unroll
            for (int j = 0; j < 4; j++) {
                int r = rb * 16 + l4 * 4 + j;
                int nd = nid[r];
                if (nd < 0) continue;
                float mean = meanl[r], inv = invl[r];
#pragma unroll
                for (int cb = 0; cb < 4; cb++) {
                    int col = colbase + cb * 16 + l15;
                    float o = (acc[rb][cb][j] - mean) * inv * lng[t * 256 + col] + lnb[t * 256 + col];
                    if (out_f32) out_f32[(size_t)nd * 256 + col] = o;
                    out_bf[(size_t)nd * 256 + col] = f2b(o);
                }
            }
        }
    }
}

// k/q/v GEMMs: blockIdx.z selects the weight set -> 3x parallelism vs fused loop
__global__ __launch_bounds__(256) void k_gemm3(
    const unsigned short* __restrict__ Abf,
    const unsigned short* __restrict__ Wt0, const unsigned short* __restrict__ Wt1,
    const unsigned short* __restrict__ Wt2,
    const float* __restrict__ b0, const float* __restrict__ b1, const float* __restrict__ b2,
    const int* __restrict__ nlist, const int* __restrict__ toff,
    unsigned short* __restrict__ o0, unsigned short* __restrict__ o1,
    unsigned short* __restrict__ o2)
{
    __shared__ unsigned short A_l[64 * LDA];
    __shared__ int nid[64];

    int t = blockIdx.y;
    int g0 = toff[t], g1 = toff[t + 1];
    int base = blockIdx.x * 64;
    int cnt = g1 - g0 - base;
    if (cnt <= 0) return;
    if (cnt > 64) cnt = 64;
    int tid = threadIdx.x;
    if (tid < 64) nid[tid] = (tid < cnt) ? nlist[g0 + base + tid] : -1;
    __syncthreads();

#pragma unroll
    for (int it = 0; it < 8; it++) {
        int id = it * 256 + tid;
        int row = id >> 5, c8 = id & 31;
        short8 v = {};
        int nd = nid[row];
        if (nd >= 0) v = *(const short8*)(Abf + (size_t)nd * 256 + c8 * 8);
        *(short8*)(A_l + row * LDA + c8 * 8) = v;
    }
    __syncthreads();

    int lane = tid & 63, wave = tid >> 6;
    int colbase = wave * 64;
    int l15 = lane & 15, l4 = lane >> 4;
    int w = blockIdx.z;
    const unsigned short* Wt = (w == 0) ? Wt0 : (w == 1) ? Wt1 : Wt2;
    const float* bs = (w == 0) ? b0 : (w == 1) ? b1 : b2;
    unsigned short* os = (w == 0) ? o0 : (w == 1) ? o1 : o2;
    f32x4 acc[4][4];
    gemm_core(A_l, Wt + (size_t)t * 65536, colbase, l15, l4, acc);
#pragma unroll
    for (int rb = 0; rb < 4; rb++) {
#pragma unroll
        for (int j = 0; j < 4; j++) {
            int r = rb * 16 + l4 * 4 + j;
            int nd = nid[r];
            if (nd < 0) continue;
#pragma unroll
            for (int cb = 0; cb < 4; cb++) {
                int col = colbase + cb * 16 + l15;
                os[(size_t)nd * 256 + col] = f2b(acc[rb][cb][j] + bs[t * 256 + col]);
            }
        }
    }
}

// ---------- q-side relation transform: rh-major [R*H][N][32], contiguous writes ----------
__global__ __launch_bounds__(256) void k_rtq(
    const unsigned short* __restrict__ qb,
    const unsigned short* __restrict__ relA,
    unsigned short* __restrict__ qrt)
{
    int tid = threadIdx.x;
    int lane = tid & 63, wave = tid >> 6;
    int l15 = lane & 15, l4 = lane >> 4;
    int h = blockIdx.y;
    int n = blockIdx.x * 64 + wave * 16 + l15;
    bool ok = (n < NN);
    short8 bfrag = {};
    if (ok) bfrag = *(const short8*)(qb + (size_t)n * 256 + h * 32 + 8 * l4);
#pragma unroll
    for (int r = 0; r < RR; r++) {
        const unsigned short* ap = relA + ((size_t)(r * HH + h)) * 1024;
        short8 a0 = *(const short8*)(ap + l15 * 32 + 8 * l4);
        short8 a1 = *(const short8*)(ap + (16 + l15) * 32 + 8 * l4);
        f32x4 c0 = {0.f, 0.f, 0.f, 0.f}, c1 = {0.f, 0.f, 0.f, 0.f};
        c0 = __builtin_amdgcn_mfma_f32_16x16x32_bf16(a0, bfrag, c0, 0, 0, 0);
        c1 = __builtin_amdgcn_mfma_f32_16x16x32_bf16(a1, bfrag, c1, 0, 0, 0);
        if (ok) {
            size_t ob = (((size_t)(r * HH + h)) * NN + n) * 32;
            us4 p0, p1;
#pragma unroll
            for (int j = 0; j < 4; j++) { p0[j] = f2b(c0[j]); p1[j] = f2b(c1[j]); }
            *(us4*)(qrt + ob + l4 * 4) = p0;
            *(us4*)(qrt + ob + 16 + l4 * 4) = p1;
        }
    }
}

// ---------- v-side relation transform: node-major [N][R*H][32], LDS-staged ----------
#define VSTRIDE 33   // us8 units per node (8h*4l4 + 1 pad) -> <=2-way LDS aliasing
__global__ __launch_bounds__(256) void k_rtv(
    const unsigned short* __restrict__ vb,
    const unsigned short* __restrict__ relMT,
    unsigned short* __restrict__ vrt)
{
    __shared__ us8 stg[4][16][VSTRIDE];
    int tid = threadIdx.x;
    int lane = tid & 63, wave = tid >> 6;
    int l15 = lane & 15, l4 = lane >> 4;
    int nbase = blockIdx.x * 64 + wave * 16;
    int n = nbase + l15;
    bool ok = (n < NN);
    short8 bfrag[8];
#pragma unroll
    for (int h = 0; h < HH; h++) {
        short8 z = {};
        bfrag[h] = ok ? *(const short8*)(vb + (size_t)n * 256 + h * 32 + 8 * l4) : z;
    }
    int nodeHalf = lane >> 5;    // 0/1
    int unit = lane & 31;        // 32 x us8 = 512B per node
    for (int r = 0; r < RR; r++) {
#pragma unroll
        for (int h = 0; h < HH; h++) {
            const unsigned short* ap = relMT + ((size_t)(r * HH + h)) * 1024;
            short8 a0 = *(const short8*)(ap + l15 * 32 + 8 * l4);
            short8 a1 = *(const short8*)(ap + (16 + l15) * 32 + 8 * l4);
            f32x4 c0 = {0.f, 0.f, 0.f, 0.f}, c1 = {0.f, 0.f, 0.f, 0.f};
            c0 = __builtin_amdgcn_mfma_f32_16x16x32_bf16(a0, bfrag[h], c0, 0, 0, 0);
            c1 = __builtin_amdgcn_mfma_f32_16x16x32_bf16(a1, bfrag[h], c1, 0, 0, 0);
            us8 pk;
#pragma unroll
            for (int j = 0; j < 4; j++) { pk[j] = f2b(c0[j]); pk[4 + j] = f2b(c1[j]); }
            stg[wave][l15][h * 4 + l4] = pk;   // wave-private; no barrier needed
        }
#pragma unroll
        for (int f = 0; f < 8; f++) {
            int node = f * 2 + nodeHalf;
            us8 v = stg[wave][node][unit];
            int gn = nbase + node;
            if (gn < NN)
                *(us8*)(vrt + (size_t)gn * 2048 + r * 256 + unit * 8) = v;
        }
    }
}

// ---------- edge scores over CSR positions (coalesced writes) ----------
__global__ void k_score(const unsigned short* __restrict__ kbf,
                        const unsigned short* __restrict__ qrt,
                        const int4* __restrict__ csr, const float* __restrict__ pri,
                        float* __restrict__ sc)
{
    int idx = blockIdx.x * 256 + threadIdx.x;
    if (idx >= EE * HH) return;
    int p = idx >> 3, h = idx & 7;
    int4 pk = csr[p];
    int s = pk.x & 0xffff, r = (pk.x >> 16) & 7;
    float w = __int_as_float(pk.y);
    int d = pk.z;
    const short8* kp = (const short8*)(kbf + (size_t)s * 256 + h * 32);
    const short8* qp = (const short8*)(qrt + (((size_t)(r * HH + h)) * NN + d) * 32);
    float acc = 0.f;
#pragma unroll
    for (int c = 0; c < 4; c++) {
        short8 a = kp[c], b = qp[c];
#pragma unroll
        for (int j = 0; j < 8; j++)
            acc += b2f((unsigned short)a[j]) * b2f((unsigned short)b[j]);
    }
    sc[idx] = acc * pri[r * HH + h] * 0.17677669529663687f * w;
}

// ---------- per-dst softmax + aggregate + gelu ----------
__global__ __launch_bounds__(256) void k_agg(
    const float* __restrict__ sc, const unsigned short* __restrict__ vrt,
    const int4* __restrict__ csr, const int* __restrict__ off,
    unsigned short* __restrict__ gbf, float* __restrict__ smaxg, float* __restrict__ ssumg)
{
    __shared__ float p_l[32][9];
    __shared__ int sbase[32];     // (src*64 + et*8)*32 ushort index base
    int n = blockIdx.x;
    int tid = threadIdx.x;
    int h = tid >> 5, i = tid & 31;
    int sp = i >> 3, dg = i & 7;
    int ob = ((dg & 1) << 4) | (((dg >> 2) & 1) << 3) | (((dg >> 1) & 1) << 2);
    int t0 = off[n], cnt = off[n + 1] - t0;
    int hoff = h * 32 + dg * 4;   // thread-constant offset inside node's 2048-elem region

    float smax = -INFINITY;
    for (int ii = i; ii < cnt; ii += 32)
        smax = fmaxf(smax, sc[(size_t)(t0 + ii) * 8 + h]);
#pragma unroll
    for (int m = 16; m >= 1; m >>= 1) smax = fmaxf(smax, __shfl_xor(smax, m, 32));

    float psum = 0.f;
    float a0 = 0.f, a1 = 0.f, a2 = 0.f, a3 = 0.f;
    for (int c0 = 0; c0 < cnt; c0 += 32) {
        int m = cnt - c0;
        if (m > 32) m = 32;
        __syncthreads();
        if (tid < m) {
            int4 pk = csr[t0 + c0 + tid];
            sbase[tid] = ((pk.x & 0xffff) * 64 + ((pk.x >> 16) & 7) * 8) * 32;
        }
        __syncthreads();
        if (i < m) {
            float p = __expf(sc[(size_t)(t0 + c0 + i) * 8 + h] - smax);
            p_l[i][h] = p;
            psum += p;
        }
        // no barrier: producer/consumer of p_l[.][h]/sbase share a 32-lane group
        for (int ii = sp; ii < m; ii += 4) {
            float p = p_l[ii][h];
            us4 v = *(const us4*)(vrt + (size_t)(unsigned)sbase[ii] + hoff);
            a0 = fmaf(p, b2f(v[0]), a0);
            a1 = fmaf(p, b2f(v[1]), a1);
            a2 = fmaf(p, b2f(v[2]), a2);
            a3 = fmaf(p, b2f(v[3]), a3);
        }
    }
#pragma unroll
    for (int m = 16; m >= 1; m >>= 1) psum += __shfl_xor(psum, m, 32);
#pragma unroll
    for (int m = 8; m <= 16; m <<= 1) {
        a0 += __shfl_xor(a0, m, 32);
        a1 += __shfl_xor(a1, m, 32);
        a2 += __shfl_xor(a2, m, 32);
        a3 += __shfl_xor(a3, m, 32);
    }
    if (i == 0) { smaxg[n * 8 + h] = smax; ssumg[n * 8 + h] = psum; }
    float den = psum + 1e-9f;
    float av = (sp == 0) ? a0 : (sp == 1) ? a1 : (sp == 2) ? a2 : a3;
    float a = av / den;
    float g = 0.5f * a * (1.f + tanhf(0.7978845608028654f * (a + 0.044715f * a * a * a)));
    gbf[(size_t)n * 256 + h * 32 + ob + sp] = f2b(g);
}

// ---------- attention output over CSR positions (last layer) ----------
__global__ void k_att(const float* __restrict__ sc, const int4* __restrict__ csr,
                      const float* __restrict__ smaxg, const float* __restrict__ ssumg,
                      float* __restrict__ att)
{
    int idx = blockIdx.x * 256 + threadIdx.x;
    if (idx >= EE * HH) return;
    int p = idx >> 3, h = idx & 7;
    int4 pk = csr[p];
    int d = pk.z, e = pk.w;
    att[(size_t)e * 8 + h] = __expf(sc[idx] - smaxg[d * 8 + h]) / (ssumg[d * 8 + h] + 1e-9f);
}

extern "C" void kernel_launch(void* const* d_in, const int* in_sizes, int n_in,
                              void* d_out, int out_size, void* d_ws, size_t ws_size,
                              hipStream_t stream)
{
    const float* nf = (const float*)d_in[0];
    const int* ntyp = (const int*)d_in[1];
    const float* ew = (const float*)d_in[2];
    const int* ei = (const int*)d_in[3];
    const int* ety = (const int*)d_in[4];
    const float* adW = (const float*)d_in[5];
    const float* adb = (const float*)d_in[6];
    const float* kW = (const float*)d_in[7];
    const float* kb = (const float*)d_in[8];
    const float* qW = (const float*)d_in[9];
    const float* qb = (const float*)d_in[10];
    const float* vW = (const float*)d_in[11];
    const float* vb = (const float*)d_in[12];
    const float* aW = (const float*)d_in[13];
    const float* ab = (const float*)d_in[14];
    const float* pri = (const float*)d_in[15];
    const float* rA = (const float*)d_in[16];
    const float* rM = (const float*)d_in[17];
    const float* skp = (const float*)d_in[18];
    const float* lng = (const float*)d_in[19];
    const float* lnb = (const float*)d_in[20];

    float* x_out = (float*)d_out;
    float* att_out = x_out + (size_t)NN * 256;

    char* wsb = (char*)d_ws;
    size_t o = 0;
    auto take = [&](size_t bytes) -> void* {
        size_t r = (o + 255) & ~(size_t)255;
        o = r + bytes;
        return (void*)(wsb + r);
    };
    unsigned short* nf_bf = (unsigned short*)take((size_t)NN * 256 * 2);
    unsigned short* x_bf = (unsigned short*)take((size_t)NN * 256 * 2);
    unsigned short* kb16 = (unsigned short*)take((size_t)NN * 256 * 2);
    unsigned short* qb16 = (unsigned short*)take((size_t)NN * 256 * 2);
    unsigned short* vb16 = (unsigned short*)take((size_t)NN * 256 * 2);
    unsigned short* gb16 = (unsigned short*)take((size_t)NN * 256 * 2);
    unsigned short* qrt = (unsigned short*)take((size_t)NN * RR * HH * 32 * 2);
    unsigned short* vrt = (unsigned short*)take((size_t)NN * RR * HH * 32 * 2);
    float* scores = (float*)take((size_t)EE * HH * 4);
    float* smaxg = (float*)take((size_t)NN * HH * 4);
    float* ssumg = (float*)take((size_t)NN * HH * 4);
    unsigned short* Wt_all = (unsigned short*)take((size_t)72 * 65536 * 2);
    unsigned short* adWt = Wt_all;
    unsigned short* kWt = Wt_all + (size_t)8 * 65536;
    unsigned short* qWt = Wt_all + (size_t)24 * 65536;
    unsigned short* vWt = Wt_all + (size_t)40 * 65536;
    unsigned short* aWt = Wt_all + (size_t)56 * 65536;
    unsigned short* relA = (unsigned short*)take((size_t)RELN * 2);
    unsigned short* relMT = (unsigned short*)take((size_t)RELN * 2);
    // zero block: deg8 (8*NN) + thist (NBN*TT)
    int* zblock = (int*)take((size_t)(8 * NN + NBN * TT) * 4);
    int* deg8 = zblock;
    int* thist = zblock + 8 * NN;
    int* base8 = (int*)take((size_t)8 * NN * 4);
    int* degT = (int*)take((size_t)NN * 4);
    int* bsum = (int*)take((size_t)NBN * 4);
    int* bbase = (int*)take((size_t)NBN * 4);
    int* rank = (int*)take((size_t)EE * 4);
    int* off = (int*)take((size_t)(NN + 1) * 4);
    int4* csr = (int4*)take((size_t)EE * 16);
    int* tboff = (int*)take((size_t)NBN * TT * 4);
    int* toff = (int*)take((TT + 1) * 4);
    int* nlist = (int*)take((size_t)NN * 4);
    if (o > ws_size) return;  // workspace insufficient — fail visibly

    hipMemsetAsync(zblock, 0, (size_t)(8 * NN + NBN * TT) * 4, stream);

    int ptot = NN * 256 + 2 * RELN;
    k_prep<<<(ptot + 255) / 256, 256, 0, stream>>>(nf, rA, rM, nf_bf, relA, relMT);
    k_transpose_all<<<dim3(8, 8, 72), dim3(32, 8), 0, stream>>>(adW, kW, qW, vW, aW, Wt_all);

    k_build1<<<(EE + 255) / 256, 256, 0, stream>>>(ei, ntyp, deg8, thist, rank);
    k_scanA<<<NBN, 256, 0, stream>>>(deg8, degT, bsum);
    k_scanB<<<1, 256, 0, stream>>>(bsum, bbase, off, thist, toff, tboff);
    k_scanC<<<NBN, 256, 0, stream>>>(deg8, degT, bbase, off, base8);
    k_build2<<<(EE + 255) / 256, 256, 0, stream>>>(ei, ety, ew, ntyp, base8, tboff, rank,
                                                   csr, nlist);

    dim3 ggrid((NN + 63) / 64, TT);
    dim3 ggrid3((NN + 63) / 64, TT, 3);
    k_gemm<0><<<ggrid, 256, 0, stream>>>(nf_bf, adWt, adb, nlist, toff,
                                         x_bf, nullptr, nullptr, nullptr, nullptr, nullptr);

    dim3 rgridq((NN + 63) / 64, HH);
    int rgridv = (NN + 63) / 64;
    int egrid = (EE * HH + 255) / 256;
    for (int l = 0; l < LLAYERS; l++) {
        k_gemm3<<<ggrid3, 256, 0, stream>>>(x_bf,
                                            kWt + (size_t)l * TT * 65536, qWt + (size_t)l * TT * 65536,
                                            vWt + (size_t)l * TT * 65536,
                                            kb + (size_t)l * TT * 256, qb + (size_t)l * TT * 256,
                                            vb + (size_t)l * TT * 256,
                                            nlist, toff, kb16, qb16, vb16);
        k_rtq<<<rgridq, 256, 0, stream>>>(qb16, relA + (size_t)l * RR * HH * 1024, qrt);
        k_rtv<<<rgridv, 256, 0, stream>>>(vb16, relMT + (size_t)l * RR * HH * 1024, vrt);
        k_score<<<egrid, 256, 0, stream>>>(kb16, qrt, csr, pri + (size_t)l * RR * HH, scores);
        k_agg<<<NN, 256, 0, stream>>>(scores, vrt, csr, off, gb16, smaxg, ssumg);
        if (l == LLAYERS - 1)
            k_att<<<egrid, 256, 0, stream>>>(scores, csr, smaxg, ssumg, att_out);
        k_gemm<2><<<ggrid, 256, 0, stream>>>(gb16, aWt + (size_t)l * TT * 65536, ab + (size_t)l * TT * 256,
                                             nlist, toff, x_bf,
                                             (l == LLAYERS - 1) ? x_out : nullptr,
                                             x_bf,
                                             skp + (size_t)l * TT, lng + (size_t)l * TT * 256, lnb + (size_t)l * TT * 256);
    }
}